// Round 4
// baseline (522.846 us; speedup 1.0000x reference)
//
#include <hip/hip_runtime.h>

#define NN 25000
#define NE 200000
#define ET (NN + NE)
#define NBLK_SCAN ((NN + 255) / 256)   // 98

__device__ __forceinline__ unsigned short f2bf(float f) {
    unsigned u = __float_as_uint(f);
    unsigned r = (u + 0x7fffu + ((u >> 16) & 1u)) >> 16;
    return (unsigned short)r;
}

// ---------- CSR build ----------
__global__ void hist_kernel(const int* __restrict__ edst, int* __restrict__ deg) {
    int e = blockIdx.x * 256 + threadIdx.x;
    if (e >= ET) return;
    int d = (e < NE) ? edst[e] : (e - NE);
    atomicAdd(&deg[d], 1);
}

// single-kernel scan: block-local inclusive scan + atomic range reservation.
// Segments are disjoint (not monotonic across blocks) — edge kernel uses deg[] for length.
__global__ void scan_atomic(const int* __restrict__ deg, int* __restrict__ soff,
                            int* __restrict__ cursor, int* __restrict__ gcount) {
    __shared__ int sh[256];
    __shared__ int base;
    int t = threadIdx.x, i = blockIdx.x * 256 + t;
    int v = (i < NN) ? deg[i] : 0;
    sh[t] = v;
    __syncthreads();
    for (int off = 1; off < 256; off <<= 1) {
        int u = (t >= off) ? sh[t - off] : 0;
        __syncthreads();
        sh[t] += u;
        __syncthreads();
    }
    if (t == 255) base = atomicAdd(gcount, sh[255]);
    __syncthreads();
    if (i < NN) {
        int ex = base + sh[t] - v;
        soff[i] = ex;
        cursor[i] = ex;
    }
}

__global__ void scatter_kernel(const int* __restrict__ esrc, const int* __restrict__ edst,
                               int* __restrict__ cursor, int* __restrict__ srcs) {
    int e = blockIdx.x * 256 + threadIdx.x;
    if (e >= ET) return;
    int s, d;
    if (e < NE) { s = esrc[e]; d = edst[e]; }
    else        { s = e - NE; d = s; }
    int p = atomicAdd(&cursor[d], 1);
    srcs[p] = s;
}

// ---------- xw = bn(x) @ W  (bf16, node-row layout [c][h]) + xu = bn(x) @ U ----------
template<int D, bool BN>
__global__ void xw_kernel(const float* __restrict__ x, const float* __restrict__ W,
                          const float* __restrict__ U, const float* __restrict__ ss,
                          unsigned short* __restrict__ xwb, float* __restrict__ xu) {
    const int NB = 8;  // 25000 % 8 == 0
    __shared__ float xs[NB][D];
    __shared__ unsigned short lt[NB][256];  // transposed bf16 rows
    int base = blockIdx.x * NB;
    int tid = threadIdx.x;
    for (int i = tid; i < NB * D; i += 256) {
        int n = i / D, k = i % D;
        float v = x[(size_t)(base + n) * D + k];
        if (BN) v = v * ss[k] + ss[64 + k];
        xs[n][k] = v;
    }
    __syncthreads();
    float acc[NB];
#pragma unroll
    for (int i = 0; i < NB; i++) acc[i] = 0.f;
    int j = tid;                 // GEMM column = h*64 + c
    int h = j >> 6, c = j & 63;
    for (int k = 0; k < D; k++) {
        float w = W[k * 256 + j];
#pragma unroll
        for (int i = 0; i < NB; i++) acc[i] += xs[i][k] * w;
    }
#pragma unroll
    for (int i = 0; i < NB; i++) lt[i][(c << 2) | h] = f2bf(acc[i]);
    // xu: threads 0..31 -> (node, head)
    if (tid < NB * 4) {
        int n = tid >> 2, hh = tid & 3;
        float s = 0.f;
        for (int k = 0; k < D; k++) s += xs[n][k] * U[k * 4 + hh];
        xu[(size_t)(base + n) * 4 + hh] = s;
    }
    __syncthreads();
    // coalesced copy: 8 rows * 512B = 4KB = 256 threads * 16B
    const uint4* s4 = (const uint4*)&lt[0][0];
    uint4* d4 = (uint4*)(xwb + (size_t)base * 256);
    d4[tid] = s4[tid];
}

// ---------- edge aggregation: wave per dst, fused BN-stat + scale/shift prep ----------
template<bool RELU_BN>
__global__ void edge_kernel(const int* __restrict__ soff, const int* __restrict__ deg,
                            const int* __restrict__ srcs,
                            const unsigned short* __restrict__ xwb, const float* __restrict__ xu,
                            const float* __restrict__ cvec, const float* __restrict__ bias,
                            float* __restrict__ y, float* __restrict__ bnpart,
                            const float* __restrict__ g, const float* __restrict__ be,
                            float* __restrict__ ss, int* __restrict__ done) {
    int wid = threadIdx.x >> 6, lane = threadIdx.x & 63;
    int d = blockIdx.x * 4 + wid;  // grid 6250 * 4 waves == 25000 exactly
    __shared__ float sbuf[4][64], sqbuf[4][64];

    float c0 = cvec[0], c1 = cvec[1], c2 = cvec[2], c3 = cvec[3];
    int cnt = deg[d];
    int beg = soff[d], end = beg + cnt;
    float4 xd = *(const float4*)&xu[(size_t)d << 2];

    // software pipeline: 1-deep data prefetch, 2-deep index prefetch
    int sn;
    float4 us;
    uint2 rv;
    {
        int s0 = srcs[beg];
        us = *(const float4*)&xu[(size_t)s0 << 2];
        rv = *(const uint2*)(xwb + ((size_t)s0 << 8) + (lane << 2));
        sn = (cnt > 1) ? srcs[beg + 1] : s0;
    }
    float acc = 0.f;
    for (int i = beg; i < end; i++) {
        float4 usn = *(const float4*)&xu[(size_t)sn << 2];
        uint2 rvn = *(const uint2*)(xwb + ((size_t)sn << 8) + (lane << 2));
        int sn2 = (i + 2 < end) ? srcs[i + 2] : sn;
        float l0 = xd.x - us.x + c0;
        float l1 = xd.y - us.y + c1;
        float l2 = xd.z - us.z + c2;
        float l3 = xd.w - us.w + c3;
        float mx = fmaxf(fmaxf(l0, l1), fmaxf(l2, l3));
        float e0 = __expf(l0 - mx), e1 = __expf(l1 - mx), e2 = __expf(l2 - mx), e3 = __expf(l3 - mx);
        float inv = 1.f / (e0 + e1 + e2 + e3);
        float w0 = __uint_as_float(rv.x << 16);
        float w1 = __uint_as_float(rv.x & 0xffff0000u);
        float w2 = __uint_as_float(rv.y << 16);
        float w3 = __uint_as_float(rv.y & 0xffff0000u);
        acc += inv * (e0 * w0 + e1 * w1 + e2 * w2 + e3 * w3);
        us = usn; rv = rvn; sn = sn2;
    }
    float v = acc / (float)cnt + bias[lane];
    if (RELU_BN) v = fmaxf(v, 0.f);
    y[(size_t)d * 64 + lane] = v;

    if (RELU_BN) {
        sbuf[wid][lane] = v;
        sqbuf[wid][lane] = v * v;
        __syncthreads();
        if (threadIdx.x < 64) {
            float ts = sbuf[0][threadIdx.x] + sbuf[1][threadIdx.x] + sbuf[2][threadIdx.x] + sbuf[3][threadIdx.x];
            float tq = sqbuf[0][threadIdx.x] + sqbuf[1][threadIdx.x] + sqbuf[2][threadIdx.x] + sqbuf[3][threadIdx.x];
            int p = blockIdx.x & 63;
            atomicAdd(&bnpart[p * 128 + threadIdx.x], ts);
            atomicAdd(&bnpart[p * 128 + 64 + threadIdx.x], tq);
        }
        // last-block-done: fold BN stats -> scale/shift, re-zero bnpart, reset counter
        __shared__ int islast;
        if (threadIdx.x == 0) {
            __threadfence();
            islast = (atomicAdd(done, 1) == (int)gridDim.x - 1);
        }
        __syncthreads();
        if (islast) {
            __threadfence();
            int t = threadIdx.x, grp = t >> 6, ch = t & 63;
            float s = 0.f, q = 0.f;
            for (int p = grp * 16; p < grp * 16 + 16; p++) {
                s += bnpart[p * 128 + ch];
                q += bnpart[p * 128 + 64 + ch];
            }
            sbuf[grp][ch] = s;
            sqbuf[grp][ch] = q;
            __syncthreads();
            if (t < 64) {
                float S = sbuf[0][t] + sbuf[1][t] + sbuf[2][t] + sbuf[3][t];
                float Q = sqbuf[0][t] + sqbuf[1][t] + sqbuf[2][t] + sqbuf[3][t];
                float m = S * (1.0f / NN);
                float var = Q * (1.0f / NN) - m * m;
                float sc = g[t] * rsqrtf(var + 1e-5f);
                ss[t] = sc;
                ss[64 + t] = be[t] - m * sc;
            }
            for (int k = t; k < 64 * 128; k += 256) bnpart[k] = 0.f;
            if (t == 0) *done = 0;
        }
    }
}

extern "C" void kernel_launch(void* const* d_in, const int* in_sizes, int n_in,
                              void* d_out, int out_size, void* d_ws, size_t ws_size,
                              hipStream_t stream) {
    const float* x    = (const float*)d_in[0];
    const int*   ei   = (const int*)d_in[1];
    const int*   esrc = ei;
    const int*   edst = ei + NE;
    const float* w0 = (const float*)d_in[2];
    const float* u0 = (const float*)d_in[3];
    const float* c0 = (const float*)d_in[4];
    const float* b0 = (const float*)d_in[5];
    const float* w1 = (const float*)d_in[6];
    const float* u1 = (const float*)d_in[7];
    const float* c1 = (const float*)d_in[8];
    const float* b1 = (const float*)d_in[9];
    const float* w2 = (const float*)d_in[10];
    const float* u2 = (const float*)d_in[11];
    const float* c2 = (const float*)d_in[12];
    const float* b2 = (const float*)d_in[13];
    const float* g0 = (const float*)d_in[14];
    const float* be0= (const float*)d_in[15];
    const float* g1 = (const float*)d_in[16];
    const float* be1= (const float*)d_in[17];
    float* out = (float*)d_out;

    char* ws = (char*)d_ws;
    size_t off = 0;
    auto alloc = [&](size_t bytes) { char* p = ws + off; off += (bytes + 255) & ~(size_t)255; return p; };
    float*          xu     = (float*)alloc((size_t)NN * 4 * sizeof(float));
    float*          y      = (float*)alloc((size_t)NN * 64 * sizeof(float));
    unsigned short* xwb    = (unsigned short*)alloc((size_t)NN * 256 * sizeof(unsigned short));
    int*            ints   = (int*)alloc((size_t)(NN + 3) * sizeof(int));  // deg | gcount | done[2]
    int*            deg    = ints;
    int*            gcount = ints + NN;
    int*            done0  = ints + NN + 1;
    int*            done1  = ints + NN + 2;
    int*            soff   = (int*)alloc((size_t)NN * sizeof(int));
    int*            cursor = (int*)alloc((size_t)NN * sizeof(int));
    int*            srcs   = (int*)alloc((size_t)ET * sizeof(int));
    float*          bnpart = (float*)alloc(64 * 128 * sizeof(float));
    float*          ss     = (float*)alloc(128 * sizeof(float));

    const int EG = (ET + 255) / 256;

    // ---- CSR build (dst-sorted; shared by all 3 layers) ----
    hipMemsetAsync(ints, 0, (size_t)(NN + 3) * sizeof(int), stream);
    hipMemsetAsync(bnpart, 0, 64 * 128 * sizeof(float), stream);
    hist_kernel<<<EG, 256, 0, stream>>>(edst, deg);
    scan_atomic<<<NBLK_SCAN, 256, 0, stream>>>(deg, soff, cursor, gcount);
    scatter_kernel<<<EG, 256, 0, stream>>>(esrc, edst, cursor, srcs);

    // ---- layer 0 (D=32, no BN on input) ----
    xw_kernel<32, false><<<NN / 8, 256, 0, stream>>>(x, w0, u0, nullptr, xwb, xu);
    edge_kernel<true><<<NN / 4, 256, 0, stream>>>(soff, deg, srcs, xwb, xu, c0, b0, y,
                                                  bnpart, g0, be0, ss, done0);

    // ---- layer 1 (D=64, BN0 applied on load) ----
    xw_kernel<64, true><<<NN / 8, 256, 0, stream>>>(y, w1, u1, ss, xwb, xu);
    edge_kernel<true><<<NN / 4, 256, 0, stream>>>(soff, deg, srcs, xwb, xu, c1, b1, y,
                                                  bnpart, g1, be1, ss, done1);

    // ---- layer 2 (D=64, BN1 applied on load, raw output) ----
    xw_kernel<64, true><<<NN / 8, 256, 0, stream>>>(y, w2, u2, ss, xwb, xu);
    edge_kernel<false><<<NN / 4, 256, 0, stream>>>(soff, deg, srcs, xwb, xu, c2, b2, out,
                                                   nullptr, nullptr, nullptr, nullptr, nullptr);
}

// Round 5
// 203.177 us; speedup vs baseline: 2.5734x; 2.5734x over previous
//
#include <hip/hip_runtime.h>

#define NN 25000
#define NE 200000
#define ET (NN + NE)
#define NBLK_SCAN ((NN + 255) / 256)   // 98

__device__ __forceinline__ unsigned short f2bf(float f) {
    unsigned u = __float_as_uint(f);
    unsigned r = (u + 0x7fffu + ((u >> 16) & 1u)) >> 16;
    return (unsigned short)r;
}

// ---------- CSR build ----------
__global__ void hist_kernel(const int* __restrict__ edst, int* __restrict__ deg) {
    int e = blockIdx.x * 256 + threadIdx.x;
    if (e >= ET) return;
    int d = (e < NE) ? edst[e] : (e - NE);
    atomicAdd(&deg[d], 1);
}

// single-kernel scan: block-local inclusive scan + atomic range reservation.
// Segments are disjoint (not monotonic across blocks) — edge kernel uses deg[] for length.
__global__ void scan_atomic(const int* __restrict__ deg, int* __restrict__ soff,
                            int* __restrict__ cursor, int* __restrict__ gcount) {
    __shared__ int sh[256];
    __shared__ int base;
    int t = threadIdx.x, i = blockIdx.x * 256 + t;
    int v = (i < NN) ? deg[i] : 0;
    sh[t] = v;
    __syncthreads();
    for (int off = 1; off < 256; off <<= 1) {
        int u = (t >= off) ? sh[t - off] : 0;
        __syncthreads();
        sh[t] += u;
        __syncthreads();
    }
    if (t == 255) base = atomicAdd(gcount, sh[255]);
    __syncthreads();
    if (i < NN) {
        int ex = base + sh[t] - v;
        soff[i] = ex;
        cursor[i] = ex;
    }
}

__global__ void scatter_kernel(const int* __restrict__ esrc, const int* __restrict__ edst,
                               int* __restrict__ cursor, int* __restrict__ srcs) {
    int e = blockIdx.x * 256 + threadIdx.x;
    if (e >= ET) return;
    int s, d;
    if (e < NE) { s = esrc[e]; d = edst[e]; }
    else        { s = e - NE; d = s; }
    int p = atomicAdd(&cursor[d], 1);
    srcs[p] = s;
}

// ---------- xw = bn(x) @ W  (bf16, node-row layout [c][h]) + xu = bn(x) @ U ----------
template<int D, bool BN>
__global__ void xw_kernel(const float* __restrict__ x, const float* __restrict__ W,
                          const float* __restrict__ U, const float* __restrict__ ss,
                          unsigned short* __restrict__ xwb, float* __restrict__ xu) {
    const int NB = 8;  // 25000 % 8 == 0
    __shared__ float xs[NB][D];
    __shared__ unsigned short lt[NB][256];  // transposed bf16 rows
    int base = blockIdx.x * NB;
    int tid = threadIdx.x;
    for (int i = tid; i < NB * D; i += 256) {
        int n = i / D, k = i % D;
        float v = x[(size_t)(base + n) * D + k];
        if (BN) v = v * ss[k] + ss[64 + k];
        xs[n][k] = v;
    }
    __syncthreads();
    float acc[NB];
#pragma unroll
    for (int i = 0; i < NB; i++) acc[i] = 0.f;
    int j = tid;                 // GEMM column = h*64 + c
    int h = j >> 6, c = j & 63;
    for (int k = 0; k < D; k++) {
        float w = W[k * 256 + j];
#pragma unroll
        for (int i = 0; i < NB; i++) acc[i] += xs[i][k] * w;
    }
#pragma unroll
    for (int i = 0; i < NB; i++) lt[i][(c << 2) | h] = f2bf(acc[i]);
    // xu: threads 0..31 -> (node, head)
    if (tid < NB * 4) {
        int n = tid >> 2, hh = tid & 3;
        float s = 0.f;
        for (int k = 0; k < D; k++) s += xs[n][k] * U[k * 4 + hh];
        xu[(size_t)(base + n) * 4 + hh] = s;
    }
    __syncthreads();
    // coalesced copy: 8 rows * 512B = 4KB = 256 threads * 16B
    const uint4* s4 = (const uint4*)&lt[0][0];
    uint4* d4 = (uint4*)(xwb + (size_t)base * 256);
    d4[tid] = s4[tid];
}

// ---------- edge aggregation: wave per dst ----------
template<bool RELU_BN>
__global__ void edge_kernel(const int* __restrict__ soff, const int* __restrict__ deg,
                            const int* __restrict__ srcs,
                            const unsigned short* __restrict__ xwb, const float* __restrict__ xu,
                            const float* __restrict__ cvec, const float* __restrict__ bias,
                            float* __restrict__ y, float* __restrict__ bnpart) {
    int wid = threadIdx.x >> 6, lane = threadIdx.x & 63;
    int d = blockIdx.x * 4 + wid;  // grid 6250 * 4 waves == 25000 exactly
    __shared__ float sbuf[4][64], sqbuf[4][64];

    float c0 = cvec[0], c1 = cvec[1], c2 = cvec[2], c3 = cvec[3];
    int cnt = deg[d];
    int beg = soff[d], end = beg + cnt;
    float4 xd = *(const float4*)&xu[(size_t)d << 2];

    // software pipeline: 1-deep data prefetch, 2-deep index prefetch
    int sn;
    float4 us;
    uint2 rv;
    {
        int s0 = srcs[beg];
        us = *(const float4*)&xu[(size_t)s0 << 2];
        rv = *(const uint2*)(xwb + ((size_t)s0 << 8) + (lane << 2));
        sn = (cnt > 1) ? srcs[beg + 1] : s0;
    }
    float acc = 0.f;
    for (int i = beg; i < end; i++) {
        float4 usn = *(const float4*)&xu[(size_t)sn << 2];
        uint2 rvn = *(const uint2*)(xwb + ((size_t)sn << 8) + (lane << 2));
        int sn2 = (i + 2 < end) ? srcs[i + 2] : sn;
        float l0 = xd.x - us.x + c0;
        float l1 = xd.y - us.y + c1;
        float l2 = xd.z - us.z + c2;
        float l3 = xd.w - us.w + c3;
        float mx = fmaxf(fmaxf(l0, l1), fmaxf(l2, l3));
        float e0 = __expf(l0 - mx), e1 = __expf(l1 - mx), e2 = __expf(l2 - mx), e3 = __expf(l3 - mx);
        float inv = 1.f / (e0 + e1 + e2 + e3);
        float w0 = __uint_as_float(rv.x << 16);
        float w1 = __uint_as_float(rv.x & 0xffff0000u);
        float w2 = __uint_as_float(rv.y << 16);
        float w3 = __uint_as_float(rv.y & 0xffff0000u);
        acc += inv * (e0 * w0 + e1 * w1 + e2 * w2 + e3 * w3);
        us = usn; rv = rvn; sn = sn2;
    }
    float v = acc / (float)cnt + bias[lane];
    if (RELU_BN) v = fmaxf(v, 0.f);
    y[(size_t)d * 64 + lane] = v;

    if (RELU_BN) {
        sbuf[wid][lane] = v;
        sqbuf[wid][lane] = v * v;
        __syncthreads();
        if (threadIdx.x < 64) {
            float ts = sbuf[0][threadIdx.x] + sbuf[1][threadIdx.x] + sbuf[2][threadIdx.x] + sbuf[3][threadIdx.x];
            float tq = sqbuf[0][threadIdx.x] + sqbuf[1][threadIdx.x] + sqbuf[2][threadIdx.x] + sqbuf[3][threadIdx.x];
            int p = blockIdx.x & 63;
            atomicAdd(&bnpart[p * 128 + threadIdx.x], ts);
            atomicAdd(&bnpart[p * 128 + 64 + threadIdx.x], tq);
        }
    }
}

// ---------- BN stats -> scale/shift; re-zeroes bnpart for the next layer ----------
__global__ void bnprep(float* __restrict__ bnpart, const float* __restrict__ g,
                       const float* __restrict__ be, float* __restrict__ ss) {
    __shared__ float sb[4][64], qb[4][64];
    int t = threadIdx.x, grp = t >> 6, ch = t & 63;
    float s = 0.f, q = 0.f;
    for (int p = grp * 16; p < grp * 16 + 16; p++) {
        s += bnpart[p * 128 + ch];
        q += bnpart[p * 128 + 64 + ch];
        bnpart[p * 128 + ch] = 0.f;
        bnpart[p * 128 + 64 + ch] = 0.f;
    }
    sb[grp][ch] = s;
    qb[grp][ch] = q;
    __syncthreads();
    if (t < 64) {
        float S = sb[0][t] + sb[1][t] + sb[2][t] + sb[3][t];
        float Q = qb[0][t] + qb[1][t] + qb[2][t] + qb[3][t];
        float m = S * (1.0f / NN);
        float var = Q * (1.0f / NN) - m * m;
        float sc = g[t] * rsqrtf(var + 1e-5f);
        ss[t] = sc;
        ss[64 + t] = be[t] - m * sc;
    }
}

extern "C" void kernel_launch(void* const* d_in, const int* in_sizes, int n_in,
                              void* d_out, int out_size, void* d_ws, size_t ws_size,
                              hipStream_t stream) {
    const float* x    = (const float*)d_in[0];
    const int*   ei   = (const int*)d_in[1];
    const int*   esrc = ei;
    const int*   edst = ei + NE;
    const float* w0 = (const float*)d_in[2];
    const float* u0 = (const float*)d_in[3];
    const float* c0 = (const float*)d_in[4];
    const float* b0 = (const float*)d_in[5];
    const float* w1 = (const float*)d_in[6];
    const float* u1 = (const float*)d_in[7];
    const float* c1 = (const float*)d_in[8];
    const float* b1 = (const float*)d_in[9];
    const float* w2 = (const float*)d_in[10];
    const float* u2 = (const float*)d_in[11];
    const float* c2 = (const float*)d_in[12];
    const float* b2 = (const float*)d_in[13];
    const float* g0 = (const float*)d_in[14];
    const float* be0= (const float*)d_in[15];
    const float* g1 = (const float*)d_in[16];
    const float* be1= (const float*)d_in[17];
    float* out = (float*)d_out;

    char* ws = (char*)d_ws;
    size_t off = 0;
    auto alloc = [&](size_t bytes) { char* p = ws + off; off += (bytes + 255) & ~(size_t)255; return p; };
    float*          xu     = (float*)alloc((size_t)NN * 4 * sizeof(float));
    float*          y      = (float*)alloc((size_t)NN * 64 * sizeof(float));
    unsigned short* xwb    = (unsigned short*)alloc((size_t)NN * 256 * sizeof(unsigned short));
    int*            ints   = (int*)alloc((size_t)(NN + 1) * sizeof(int));  // deg | gcount
    int*            deg    = ints;
    int*            gcount = ints + NN;
    int*            soff   = (int*)alloc((size_t)NN * sizeof(int));
    int*            cursor = (int*)alloc((size_t)NN * sizeof(int));
    int*            srcs   = (int*)alloc((size_t)ET * sizeof(int));
    float*          bnpart = (float*)alloc(64 * 128 * sizeof(float));
    float*          ss     = (float*)alloc(128 * sizeof(float));

    const int EG = (ET + 255) / 256;

    // ---- CSR build (dst-sorted; shared by all 3 layers) ----
    hipMemsetAsync(ints, 0, (size_t)(NN + 1) * sizeof(int), stream);
    hipMemsetAsync(bnpart, 0, 64 * 128 * sizeof(float), stream);
    hist_kernel<<<EG, 256, 0, stream>>>(edst, deg);
    scan_atomic<<<NBLK_SCAN, 256, 0, stream>>>(deg, soff, cursor, gcount);
    scatter_kernel<<<EG, 256, 0, stream>>>(esrc, edst, cursor, srcs);

    // ---- layer 0 (D=32, no BN on input) ----
    xw_kernel<32, false><<<NN / 8, 256, 0, stream>>>(x, w0, u0, nullptr, xwb, xu);
    edge_kernel<true><<<NN / 4, 256, 0, stream>>>(soff, deg, srcs, xwb, xu, c0, b0, y, bnpart);
    bnprep<<<1, 256, 0, stream>>>(bnpart, g0, be0, ss);

    // ---- layer 1 (D=64, BN0 applied on load) ----
    xw_kernel<64, true><<<NN / 8, 256, 0, stream>>>(y, w1, u1, ss, xwb, xu);
    edge_kernel<true><<<NN / 4, 256, 0, stream>>>(soff, deg, srcs, xwb, xu, c1, b1, y, bnpart);
    bnprep<<<1, 256, 0, stream>>>(bnpart, g1, be1, ss);

    // ---- layer 2 (D=64, BN1 applied on load, raw output) ----
    xw_kernel<64, true><<<NN / 8, 256, 0, stream>>>(y, w2, u2, ss, xwb, xu);
    edge_kernel<false><<<NN / 4, 256, 0, stream>>>(soff, deg, srcs, xwb, xu, c2, b2, out, nullptr);
}